// Round 7
// baseline (133.683 us; speedup 1.0000x reference)
//
#include <hip/hip_runtime.h>
#include <math.h>

#define HH 512
#define WW 512
#define HW (HH*WW)   // 262144

__device__ __forceinline__ int refl(int i) {
  if (i < 0) return -i;
  if (i >= HH) return 2*HH - 2 - i;
  return i;
}

__device__ __forceinline__ float sumsq3(float r, float g, float b) {
  return __fadd_rn(__fadd_rn(__fmul_rn(r,r), __fmul_rn(g,g)), __fmul_rn(b,b));
}

// K1: global max of per-pixel channel sum-of-squares (max-only, no ss store).
// Max over the same multiset as R6 -> bit-identical scalar.
__global__ __launch_bounds__(256) void k1_max(const float* __restrict__ img,
                                              float* __restrict__ partials) {
  int t = blockIdx.x * 256 + threadIdx.x;      // 2048 blocks -> 524288 threads
  float m = 0.0f;
  #pragma unroll
  for (int i = 0; i < 2; ++i) {
    int gid = t + i * 524288;                  // 1048576 float4 granules total
    int n  = gid >> 16;
    int p4 = gid & 65535;
    const float* base = img + (size_t)n * 3 * HW;
    float4 r = ((const float4*)(base        ))[p4];
    float4 g = ((const float4*)(base +   HW ))[p4];
    float4 b = ((const float4*)(base + 2*HW ))[p4];
    float sx = sumsq3(r.x, g.x, b.x);
    float sy = sumsq3(r.y, g.y, b.y);
    float sz = sumsq3(r.z, g.z, b.z);
    float sw = sumsq3(r.w, g.w, b.w);
    m = fmaxf(m, fmaxf(fmaxf(sx, sy), fmaxf(sz, sw)));
  }
  #pragma unroll
  for (int off = 32; off > 0; off >>= 1)
    m = fmaxf(m, __shfl_down(m, off));
  __shared__ float sm[4];
  int lane = threadIdx.x & 63, wv = threadIdx.x >> 6;
  if (lane == 0) sm[wv] = m;
  __syncthreads();
  if (threadIdx.x == 0)
    partials[blockIdx.x] = fmaxf(fmaxf(sm[0], sm[1]), fmaxf(sm[2], sm[3]));
}

// K1b: reduce 2048 partials -> ssmax (single block, no atomics)
__global__ __launch_bounds__(256) void k1b_reduce(const float* __restrict__ partials,
                                                  float* __restrict__ ssmax) {
  float m = 0.0f;
  #pragma unroll
  for (int i = 0; i < 8; ++i)
    m = fmaxf(m, partials[threadIdx.x + 256 * i]);
  #pragma unroll
  for (int off = 32; off > 0; off >>= 1)
    m = fmaxf(m, __shfl_down(m, off));
  __shared__ float sm[4];
  int lane = threadIdx.x & 63, wv = threadIdx.x >> 6;
  if (lane == 0) sm[wv] = m;
  __syncthreads();
  if (threadIdx.x == 0)
    ssmax[0] = fmaxf(fmaxf(sm[0], sm[1]), fmaxf(sm[2], sm[3]));
}

// K3: fully fused: img -> mag (LDS, identical sumsq3/sqrt/div formula) ->
// 5x5 Sobel via R6's symmetry-restructured f64 formula, computed per-pixel
// over an 18x66 gm tile (64x16 centers + ring-1 halo, all in LDS) ->
// sobel/phase for centers -> NMS + threshold -> edges.
// Ring gm recompute uses a different f64 summation order than a neighbor
// block's center compute; per R6's validated model the f64 noise (~1e-16 rel)
// survives f64->f32 rounding with prob ~1e-9/value -> f32-bit-equal.
__global__ __launch_bounds__(256) void k3_fused(const float* __restrict__ img,
                                                const float* __restrict__ ssmax,
                                                float* __restrict__ sobel_out,
                                                float* __restrict__ edges) {
  __shared__ float magS[22 * 72];        // rows y0-3..y0+18, cols x0-3..x0+66
  __shared__ float gmS[18 * 68];         // gm rows y0-1..y0+16, cols x0-1..x0+64
  __shared__ unsigned char pairS[16 * 64];

  int tid = threadIdx.y * 64 + threadIdx.x;   // block 64x4 = 256
  int x0 = blockIdx.x * 64;
  int y0 = blockIdx.y * 16;
  int n  = blockIdx.z;
  const float* base = img + (size_t)n * 3 * HW;
  float mm = sqrtf(ssmax[0]);

  // ---- stage normalized mag: 22 rows x 70 cols ----
  for (int i = tid; i < 22 * 70; i += 256) {
    int r = i / 70, c = i - r * 70;
    int gy = refl(y0 - 3 + r);
    int gx = refl(x0 - 3 + c);
    int gp = gy * WW + gx;
    float ssv = sumsq3(base[gp], base[HW + gp], base[2 * HW + gp]);
    magS[r * 72 + c] = __fdiv_rn(sqrtf(ssv), mm);   // bit-identical mag vs R6
  }
  __syncthreads();

  // exact f32 weights (numpy-folded), widened to f64 exactly
  const double wA0 = (double)(-2.0f/8.0f/6.0f);
  const double wA1 = (double)(-2.0f/5.0f/6.0f);
  const double wA2 = (double)(-2.0f/1.0f/6.0f);
  const double wB0 = (double)(-1.0f/5.0f/6.0f);
  const double wB1 = (double)(-1.0f/2.0f/6.0f);
  const double wB2 = (double)(-1.0f/1.0f/6.0f);

  // ---- gm over 18x66 (centers + ring); sobel/pair for centers ----
  for (int i = tid; i < 18 * 66; i += 256) {
    int gr = i / 66, gc = i - gr * 66;   // gm-local coords
    // output pixel (y,x) = (y0+gr-1, x0+gc-1); mag window rows gr..gr+4,
    // cols gc..gc+4 in magS coords.
    double S[5], T[5], C[5], D0[5], D1[5];
    #pragma unroll
    for (int a = 0; a < 5; ++a) {
      const float* rowp = &magS[(gr + a) * 72 + gc];
      double v0 = (double)rowp[0], v1 = (double)rowp[1], v2 = (double)rowp[2],
             v3 = (double)rowp[3], v4 = (double)rowp[4];
      S[a]  = v0 + v4;  T[a]  = v1 + v3;  C[a] = v2;
      D0[a] = v0 - v4;  D1[a] = v1 - v3;
    }
    double asy = wA0*(S[0]-S[4]) + wA1*(T[0]-T[4]) + wA2*(C[0]-C[4])
               + wB0*(S[1]-S[3]) + wB1*(T[1]-T[3]) + wB2*(C[1]-C[3]);
    double asx = wA0*(D0[0]+D0[4]) + wA1*(D0[1]+D0[3]) + wA2*D0[2]
               + wB0*(D1[0]+D1[4]) + wB1*(D1[1]+D1[3]) + wB2*D1[2];
    float fsy = (float)asy, fsx = (float)asx;
    float g = sqrtf(__fadd_rn(__fmul_rn(fsx, fsx), __fmul_rn(fsy, fsy)));
    gmS[gr * 68 + gc] = g;
    int cy = gr - 1, cx = gc - 1;        // tile-local center coords
    if (cy >= 0 && cy < 16 && cx >= 0 && cx < 64) {
      size_t p = (size_t)n * 2 * HW + (size_t)(y0 + cy) * WW + (x0 + cx);
      sobel_out[p]      = fsy;           // channel 0: sobel_y
      sobel_out[p + HW] = fsx;           // channel 1: sobel_x
      float ph = atan2f(fsx, __fadd_rn(fsy, 1e-5f));
      float pf = __fdiv_rn(ph, 0.78539816339744830962f);  // f32(pi/4)
      float rr = rintf(pf);                                // half-to-even
      int ip = ((int)rr + 4) & 7;
      pairS[cy * 64 + cx] = (unsigned char)(ip & 3);       // SEL_IDS period 4
    }
  }
  __syncthreads();

  // ---- NMS + threshold (logic source-identical to R6 k4, gm from LDS) ----
  const int dy0[4] = {-1, -1,  0, -1};
  const int dx0[4] = { 0, -1, -1,  1};
  const int dy1[4] = { 1,  1,  0,  1};
  const int dx1[4] = { 0,  1,  1, -1};
  for (int i = tid; i < 16 * 64; i += 256) {
    int cy = i >> 6, cx = i & 63;
    int y = y0 + cy, x = x0 + cx;
    float g = gmS[(cy + 1) * 68 + (cx + 1)];
    int pr = pairS[cy * 64 + cx];
    int yA = y + dy0[pr], xA = x + dx0[pr];
    int yB = y + dy1[pr], xB = x + dx1[pr];
    float n0 = (yA >= 0 && yA < HH && xA >= 0 && xA < WW)
             ? gmS[(cy + 1 + dy0[pr]) * 68 + (cx + 1 + dx0[pr])] : 0.0f;
    float n1 = (yB >= 0 && yB < HH && xB >= 0 && xB < WW)
             ? gmS[(cy + 1 + dy1[pr]) * 68 + (cx + 1 + dx1[pr])] : 0.0f;
    bool mask = (g <= n0) || (g < n1);
    edges[(size_t)n * HW + (size_t)y * WW + x] = (!mask && (g > 0.1f)) ? 1.0f : 0.0f;
  }
}

extern "C" void kernel_launch(void* const* d_in, const int* in_sizes, int n_in,
                              void* d_out, int out_size, void* d_ws, size_t ws_size,
                              hipStream_t stream) {
  const float* img = (const float*)d_in[0];
  float* out = (float*)d_out;
  char* ws = (char*)d_ws;

  float* ssmax    = (float*)ws;            // 4 B (region padded to 256 B)
  float* partials = (float*)(ws + 256);    // 2048 floats

  float* edges = out;                      // (16,1,512,512)
  float* sobel = out + 4194304;            // (16,2,512,512): c0=sy, c1=sx

  k1_max    <<<dim3(2048), dim3(256), 0, stream>>>(img, partials);
  k1b_reduce<<<dim3(1),    dim3(256), 0, stream>>>(partials, ssmax);
  k3_fused  <<<dim3(8, 32, 16), dim3(64, 4), 0, stream>>>(img, ssmax, sobel, edges);
}